// Round 1
// baseline (233.802 us; speedup 1.0000x reference)
//
#include <hip/hip_runtime.h>
#include <hip/hip_bf16.h>
#include <cstdint>

#define N_SRC 100000
#define N_DST 25000
#define N_EDGE 300000
// D_IN = D_HID = D_OUT = 256, concat K = 512

typedef float f32x4 __attribute__((ext_vector_type(4)));
typedef __bf16 bf16x8 __attribute__((ext_vector_type(8)));

__device__ __forceinline__ unsigned short f2bf(float f) {
    union { float f; unsigned int u; } v; v.f = f;
    unsigned int u = v.u;
    u += 0x7FFFu + ((u >> 16) & 1u);   // RNE; inputs finite
    return (unsigned short)(u >> 16);
}
__device__ __forceinline__ float bf2f(unsigned int bits16) {
    union { unsigned int u; float f; } v; v.u = bits16 << 16;
    return v.f;
}

// ---- cast + transpose weights: Qt[n][k] = bf16(Q_w[k][n]), Wt[n][k] = bf16(W_w[k][n])
__global__ void cast_weights(const float* __restrict__ Qw, const float* __restrict__ Ww,
                             unsigned short* __restrict__ Qt, unsigned short* __restrict__ Wt) {
    int i = blockIdx.x * blockDim.x + threadIdx.x;
    if (i < 256 * 256) {
        int n = i >> 8, k = i & 255;
        Qt[n * 256 + k] = f2bf(Qw[k * 256 + n]);
    } else if (i < 256 * 256 + 512 * 256) {
        int j = i - 256 * 256;
        int n = j >> 9, k = j & 511;
        Wt[n * 512 + k] = f2bf(Ww[k * 256 + n]);
    }
}

// ---- CSR build: histogram, scan, scatter
__global__ void hist_kernel(const int* __restrict__ dst_idx, int* __restrict__ counts) {
    int i = blockIdx.x * blockDim.x + threadIdx.x;
    if (i < N_EDGE) atomicAdd(&counts[dst_idx[i]], 1);
}

__global__ void scan_kernel(const int* __restrict__ counts, int* __restrict__ offsets, int n) {
    __shared__ int buf[1024];
    __shared__ int carry_s;
    int t = threadIdx.x;
    if (t == 0) { carry_s = 0; offsets[0] = 0; }
    __syncthreads();
    for (int base = 0; base < n; base += 1024) {
        int x = (base + t < n) ? counts[base + t] : 0;
        buf[t] = x;
        __syncthreads();
        for (int off = 1; off < 1024; off <<= 1) {
            int y = (t >= off) ? buf[t - off] : 0;
            __syncthreads();
            buf[t] += y;
            __syncthreads();
        }
        int incl = buf[t];
        int carry = carry_s;
        if (base + t < n) offsets[base + t + 1] = carry + incl;
        __syncthreads();
        if (t == 0) carry_s = carry + buf[1023];
        __syncthreads();
    }
}

__global__ void scatter_kernel(const int* __restrict__ dst_idx, const int* __restrict__ offsets,
                               int* __restrict__ cursor, int* __restrict__ edge_list) {
    int i = blockIdx.x * blockDim.x + threadIdx.x;
    if (i < N_EDGE) {
        int d = dst_idx[i];
        int pos = offsets[d] + atomicAdd(&cursor[d], 1);
        edge_list[pos] = i;
    }
}

// ---- fused GEMM: C = relu(A @ B + bias), optional row-L2-normalize epilogue.
// A: [M][KDIM] f32 (convert while staging) or bf16. Bt: [256][KDIM] bf16 (pre-transposed).
// Block: 256 thr = 4 waves; tile 64(M) x 256(N); wave w owns cols w*64..w*64+63.
template<int KDIM, bool A_BF16, bool NORM>
__global__ __launch_bounds__(256) void gemm_fused(
    const float* __restrict__ Af, const unsigned short* __restrict__ Ab,
    const unsigned short* __restrict__ Bt, const float* __restrict__ bias,
    unsigned short* __restrict__ Cb, float* __restrict__ Cf, int M)
{
    __shared__ __align__(16) unsigned short As[64 * 72];   // pad: 144B row stride
    __shared__ __align__(16) unsigned short Bs[256 * 72];  // transposed: Bs[n][k]
    __shared__ float norml[4][64];

    const int tid = threadIdx.x;
    const int wave = tid >> 6, lane = tid & 63;
    const int g = lane >> 4, c = lane & 15;
    const int wn0 = wave * 64;
    const int m0 = blockIdx.x * 64;

    f32x4 acc[4][4];
    for (int i = 0; i < 4; ++i)
        for (int j = 0; j < 4; ++j)
            acc[i][j] = (f32x4){0.f, 0.f, 0.f, 0.f};

    for (int kt = 0; kt < KDIM / 64; ++kt) {
        const int k0 = kt * 64;
        if constexpr (A_BF16) {
            for (int i = 0; i < 2; ++i) {
                int idx = tid + i * 256;
                int row = idx >> 3, ch = idx & 7;
                int gm = m0 + row;
                uint4 v = {0u, 0u, 0u, 0u};
                if (gm < M) v = *reinterpret_cast<const uint4*>(Ab + (size_t)gm * KDIM + k0 + ch * 8);
                *reinterpret_cast<uint4*>(&As[row * 72 + ch * 8]) = v;
            }
        } else {
            for (int i = 0; i < 4; ++i) {
                int idx = tid + i * 256;
                int row = idx >> 4, f4 = idx & 15;
                int gm = m0 + row;
                float x0 = 0.f, x1 = 0.f, x2 = 0.f, x3 = 0.f;
                if (gm < M) {
                    const float4 v = *reinterpret_cast<const float4*>(Af + (size_t)gm * KDIM + k0 + f4 * 4);
                    x0 = v.x; x1 = v.y; x2 = v.z; x3 = v.w;
                }
                uint2 p;
                p.x = (unsigned)f2bf(x0) | ((unsigned)f2bf(x1) << 16);
                p.y = (unsigned)f2bf(x2) | ((unsigned)f2bf(x3) << 16);
                *reinterpret_cast<uint2*>(&As[row * 72 + f4 * 4]) = p;
            }
        }
        for (int i = 0; i < 8; ++i) {
            int idx = tid + i * 256;
            int n = idx >> 3, ch = idx & 7;
            uint4 v = *reinterpret_cast<const uint4*>(Bt + (size_t)n * KDIM + k0 + ch * 8);
            *reinterpret_cast<uint4*>(&Bs[n * 72 + ch * 8]) = v;
        }
        __syncthreads();
        for (int ks = 0; ks < 2; ++ks) {
            const int koff = ks * 32 + g * 8;
            bf16x8 a[4], b[4];
            for (int mi = 0; mi < 4; ++mi)
                a[mi] = *reinterpret_cast<const bf16x8*>(&As[(mi * 16 + c) * 72 + koff]);
            for (int ni = 0; ni < 4; ++ni)
                b[ni] = *reinterpret_cast<const bf16x8*>(&Bs[(wn0 + ni * 16 + c) * 72 + koff]);
            for (int mi = 0; mi < 4; ++mi)
                for (int ni = 0; ni < 4; ++ni)
                    acc[mi][ni] = __builtin_amdgcn_mfma_f32_16x16x32_bf16(a[mi], b[ni], acc[mi][ni], 0, 0, 0);
        }
        __syncthreads();
    }

    float bcol[4];
    for (int ni = 0; ni < 4; ++ni) bcol[ni] = bias[wn0 + ni * 16 + c];

    if constexpr (!NORM) {
        for (int mi = 0; mi < 4; ++mi) {
            int rowb = m0 + mi * 16 + g * 4;
            for (int ni = 0; ni < 4; ++ni) {
                int col = wn0 + ni * 16 + c;
                for (int r = 0; r < 4; ++r) {
                    int row = rowb + r;
                    if (row < M) {
                        float v = fmaxf(acc[mi][ni][r] + bcol[ni], 0.f);
                        Cb[(size_t)row * 256 + col] = f2bf(v);
                    }
                }
            }
        }
    } else {
        float ssq[4][4];
        for (int mi = 0; mi < 4; ++mi) {
            for (int r = 0; r < 4; ++r) {
                float s = 0.f;
                for (int ni = 0; ni < 4; ++ni) {
                    float v = fmaxf(acc[mi][ni][r] + bcol[ni], 0.f);
                    acc[mi][ni][r] = v;
                    s += v * v;
                }
                for (int m = 1; m < 16; m <<= 1) s += __shfl_xor(s, m, 64);
                ssq[mi][r] = s;
            }
        }
        if (c == 0) {
            for (int mi = 0; mi < 4; ++mi)
                for (int r = 0; r < 4; ++r)
                    norml[wave][mi * 16 + g * 4 + r] = ssq[mi][r];
        }
        __syncthreads();
        for (int mi = 0; mi < 4; ++mi) {
            int rowb = m0 + mi * 16 + g * 4;
            for (int r = 0; r < 4; ++r) {
                int rl = mi * 16 + g * 4 + r;
                float tot = norml[0][rl] + norml[1][rl] + norml[2][rl] + norml[3][rl];
                float rn = tot > 0.f ? rsqrtf(tot) : 1.0f;
                int row = rowb + r;
                if (row < M) {
                    for (int ni = 0; ni < 4; ++ni) {
                        int col = wn0 + ni * 16 + c;
                        Cf[(size_t)row * 256 + col] = acc[mi][ni][r] * rn;
                    }
                }
            }
        }
    }
}

// ---- per-dst aggregation: one wave per dst; xb[d] = concat(bf16(n/max(ws,1)), bf16(h_dst[d]))
__global__ __launch_bounds__(256) void aggregate_kernel(
    const unsigned short* __restrict__ nft, const float* __restrict__ h_dst,
    const float* __restrict__ weights, const int* __restrict__ src_idx,
    const int* __restrict__ edge_list, const int* __restrict__ offsets,
    unsigned short* __restrict__ xb)
{
    int d = blockIdx.x * 4 + (threadIdx.x >> 6);
    if (d >= N_DST) return;
    int lane = threadIdx.x & 63;
    int p0 = offsets[d], p1 = offsets[d + 1];
    float a0 = 0.f, a1 = 0.f, a2 = 0.f, a3 = 0.f, wsum = 0.f;
    for (int p = p0; p < p1; ++p) {
        int e = edge_list[p];
        float w = weights[e];
        int s = src_idx[e];
        wsum += w;
        uint2 v = *reinterpret_cast<const uint2*>(nft + (size_t)s * 256 + lane * 4);
        a0 += w * bf2f(v.x & 0xffffu);
        a1 += w * bf2f(v.x >> 16);
        a2 += w * bf2f(v.y & 0xffffu);
        a3 += w * bf2f(v.y >> 16);
    }
    float inv = 1.0f / fmaxf(wsum, 1.0f);
    uint2 p;
    p.x = (unsigned)f2bf(a0 * inv) | ((unsigned)f2bf(a1 * inv) << 16);
    p.y = (unsigned)f2bf(a2 * inv) | ((unsigned)f2bf(a3 * inv) << 16);
    *reinterpret_cast<uint2*>(xb + (size_t)d * 512 + lane * 4) = p;
    float4 h = *reinterpret_cast<const float4*>(h_dst + (size_t)d * 256 + lane * 4);
    uint2 q;
    q.x = (unsigned)f2bf(h.x) | ((unsigned)f2bf(h.y) << 16);
    q.y = (unsigned)f2bf(h.z) | ((unsigned)f2bf(h.w) << 16);
    *reinterpret_cast<uint2*>(xb + (size_t)d * 512 + 256 + lane * 4) = q;
}

extern "C" void kernel_launch(void* const* d_in, const int* in_sizes, int n_in,
                              void* d_out, int out_size, void* d_ws, size_t ws_size,
                              hipStream_t stream) {
    const float* h_src   = (const float*)d_in[0];
    const float* h_dst   = (const float*)d_in[1];
    const float* weights = (const float*)d_in[2];
    const float* Q_w     = (const float*)d_in[3];
    const float* Q_b     = (const float*)d_in[4];
    const float* W_w     = (const float*)d_in[5];
    const float* W_b     = (const float*)d_in[6];
    const int* src_idx   = (const int*)d_in[7];
    const int* dst_idx   = (const int*)d_in[8];
    float* out = (float*)d_out;

    char* ws = (char*)d_ws;
    unsigned short* nft = (unsigned short*)(ws);               // 100000*256*2 = 51,200,000
    unsigned short* xb  = (unsigned short*)(ws + 51200000);    // 25000*512*2  = 25,600,000
    unsigned short* Qt  = (unsigned short*)(ws + 76800000);    // 131,072
    unsigned short* Wt  = (unsigned short*)(ws + 76931072);    // 262,144
    int* counts    = (int*)(ws + 77193216);                    // 100,000
    int* offsets   = (int*)(ws + 77293216);                    // 100,004
    int* cursor    = (int*)(ws + 77393220);                    // 100,000
    int* edge_list = (int*)(ws + 77493220);                    // 1,200,000  (total ~78.7 MB)

    hipMemsetAsync(counts, 0, N_DST * sizeof(int), stream);
    hipMemsetAsync(cursor, 0, N_DST * sizeof(int), stream);

    cast_weights<<<768, 256, 0, stream>>>(Q_w, W_w, Qt, Wt);
    hist_kernel<<<(N_EDGE + 255) / 256, 256, 0, stream>>>(dst_idx, counts);
    scan_kernel<<<1, 1024, 0, stream>>>(counts, offsets, N_DST);
    scatter_kernel<<<(N_EDGE + 255) / 256, 256, 0, stream>>>(dst_idx, offsets, cursor, edge_list);

    gemm_fused<256, false, false><<<(N_SRC + 63) / 64, 256, 0, stream>>>(
        h_src, nullptr, Qt, Q_b, nft, nullptr, N_SRC);

    aggregate_kernel<<<N_DST / 4, 256, 0, stream>>>(
        nft, h_dst, weights, src_idx, edge_list, offsets, xb);

    gemm_fused<512, true, true><<<(N_DST + 63) / 64, 256, 0, stream>>>(
        nullptr, xb, Wt, W_b, nullptr, out, N_DST);

    (void)in_sizes; (void)n_in; (void)out_size; (void)ws_size;
}

// Round 2
// 188.755 us; speedup vs baseline: 1.2387x; 1.2387x over previous
//
#include <hip/hip_runtime.h>
#include <hip/hip_bf16.h>
#include <cstdint>

#define N_SRC 100000
#define N_DST 25000
#define N_EDGE 300000
// D_IN = D_HID = D_OUT = 256, concat K = 512

typedef float f32x4 __attribute__((ext_vector_type(4)));
typedef __bf16 bf16x8 __attribute__((ext_vector_type(8)));

__device__ __forceinline__ unsigned short f2bf(float f) {
    union { float f; unsigned int u; } v; v.f = f;
    unsigned int u = v.u;
    u += 0x7FFFu + ((u >> 16) & 1u);   // RNE; inputs finite
    return (unsigned short)(u >> 16);
}
__device__ __forceinline__ float bf2f(unsigned int bits16) {
    union { unsigned int u; float f; } v; v.u = bits16 << 16;
    return v.f;
}

// ---- cast + transpose weights: Qt[n][k] = bf16(Q_w[k][n]), Wt[n][k] = bf16(W_w[k][n])
__global__ void cast_weights(const float* __restrict__ Qw, const float* __restrict__ Ww,
                             unsigned short* __restrict__ Qt, unsigned short* __restrict__ Wt) {
    int i = blockIdx.x * blockDim.x + threadIdx.x;
    if (i < 256 * 256) {
        int n = i >> 8, k = i & 255;
        Qt[n * 256 + k] = f2bf(Qw[k * 256 + n]);
    } else if (i < 256 * 256 + 512 * 256) {
        int j = i - 256 * 256;
        int n = j >> 9, k = j & 511;
        Wt[n * 512 + k] = f2bf(Ww[k * 256 + n]);
    }
}

// ---- CSR build: histogram, scan, scatter (cursor folded into counts via atomicSub)
__global__ void hist_kernel(const int* __restrict__ dst_idx, int* __restrict__ counts) {
    int i = blockIdx.x * blockDim.x + threadIdx.x;
    if (i < N_EDGE) atomicAdd(&counts[dst_idx[i]], 1);
}

// single block, 1024 thr = 16 waves; shfl-based scan, 3 barriers per 1024-chunk
__global__ __launch_bounds__(1024) void scan_kernel(const int* __restrict__ counts,
                                                    int* __restrict__ offsets, int n) {
    __shared__ int wsum[16];
    const int t = threadIdx.x;
    const int wid = t >> 6, lane = t & 63;
    int carry = 0;
    if (t == 0) offsets[0] = 0;
    for (int base = 0; base < n; base += 1024) {
        int x = (base + t < n) ? counts[base + t] : 0;
        #pragma unroll
        for (int off = 1; off < 64; off <<= 1) {
            int y = __shfl_up(x, off, 64);
            if (lane >= off) x += y;
        }
        if (lane == 63) wsum[wid] = x;
        __syncthreads();
        if (t < 16) {
            int w = wsum[t];
            #pragma unroll
            for (int off = 1; off < 16; off <<= 1) {
                int y = __shfl_up(w, off, 64);
                if (t >= off) w += y;
            }
            wsum[t] = w;
        }
        __syncthreads();
        int pre = (wid > 0) ? wsum[wid - 1] : 0;
        int incl = carry + pre + x;
        if (base + t < n) offsets[base + t + 1] = incl;
        carry += wsum[15];
        __syncthreads();   // wsum reused next chunk
    }
}

__global__ void scatter_kernel(const int* __restrict__ dst_idx, const int* __restrict__ offsets,
                               int* __restrict__ counts, int* __restrict__ edge_list) {
    int i = blockIdx.x * blockDim.x + threadIdx.x;
    if (i < N_EDGE) {
        int d = dst_idx[i];
        int pos = offsets[d] + (atomicSub(&counts[d], 1) - 1);
        edge_list[pos] = i;
    }
}

// ---- fused GEMM: C = relu(A @ B + bias), optional row-L2-normalize epilogue.
// 2-phase pipeline: B frags direct global->reg (L2-resident), A reg-staged into
// dbuf LDS (issue-early / write-late), one barrier per k-tile.
// Block: 256 thr = 4 waves; tile 64(M) x 256(N); wave w owns cols w*64..+63.
template<int KDIM, bool A_BF16, bool NORM>
__global__ __launch_bounds__(256, 2) void gemm_fused(
    const float* __restrict__ Af, const unsigned short* __restrict__ Ab,
    const unsigned short* __restrict__ Bt, const float* __restrict__ bias,
    unsigned short* __restrict__ Cb, float* __restrict__ Cf, int M)
{
    constexpr int NKT = KDIM / 64;
    __shared__ __align__(16) unsigned short As[2][64 * 72];  // 144B row stride
    __shared__ float norml[4][64];

    const int tid = threadIdx.x;
    const int wave = tid >> 6, lane = tid & 63;
    const int g = lane >> 4, c = lane & 15;
    const int wn0 = wave * 64;
    const int m0 = blockIdx.x * 64;

    f32x4 acc[4][4];
    #pragma unroll
    for (int i = 0; i < 4; ++i)
        #pragma unroll
        for (int j = 0; j < 4; ++j)
            acc[i][j] = (f32x4){0.f, 0.f, 0.f, 0.f};

    float4 sf[4];   // f32 staging regs (GEMM1)
    uint4  sb[2];   // bf16 staging regs (GEMM2)

    auto issueA = [&](int kt) {
        const int k0 = kt * 64;
        if constexpr (A_BF16) {
            #pragma unroll
            for (int i = 0; i < 2; ++i) {
                int idx = tid + i * 256;
                int row = idx >> 3, ch = idx & 7;
                int gm = min(m0 + row, M - 1);
                sb[i] = *reinterpret_cast<const uint4*>(Ab + (size_t)gm * KDIM + k0 + ch * 8);
            }
        } else {
            #pragma unroll
            for (int i = 0; i < 4; ++i) {
                int idx = tid + i * 256;
                int row = idx >> 4, c4 = idx & 15;
                int gm = min(m0 + row, M - 1);
                sf[i] = *reinterpret_cast<const float4*>(Af + (size_t)gm * KDIM + k0 + c4 * 4);
            }
        }
    };
    auto writeA = [&](int buf) {
        if constexpr (A_BF16) {
            #pragma unroll
            for (int i = 0; i < 2; ++i) {
                int idx = tid + i * 256;
                int row = idx >> 3, ch = idx & 7;
                *reinterpret_cast<uint4*>(&As[buf][row * 72 + ch * 8]) = sb[i];
            }
        } else {
            #pragma unroll
            for (int i = 0; i < 4; ++i) {
                int idx = tid + i * 256;
                int row = idx >> 4, c4 = idx & 15;
                uint2 p;
                p.x = (unsigned)f2bf(sf[i].x) | ((unsigned)f2bf(sf[i].y) << 16);
                p.y = (unsigned)f2bf(sf[i].z) | ((unsigned)f2bf(sf[i].w) << 16);
                *reinterpret_cast<uint2*>(&As[buf][row * 72 + c4 * 4]) = p;
            }
        }
    };

    issueA(0);
    writeA(0);
    __syncthreads();

    #pragma unroll
    for (int kt = 0; kt < NKT; ++kt) {
        const int cur = kt & 1;
        if (kt + 1 < NKT) issueA(kt + 1);      // issue next A tile early (T14)
        const int k0 = kt * 64;
        bf16x8 bfrag[2][4];                     // B direct from global (L2)
        #pragma unroll
        for (int ks = 0; ks < 2; ++ks)
            #pragma unroll
            for (int ni = 0; ni < 4; ++ni)
                bfrag[ks][ni] = *reinterpret_cast<const bf16x8*>(
                    Bt + (size_t)(wn0 + ni * 16 + c) * KDIM + k0 + ks * 32 + g * 8);
        #pragma unroll
        for (int ks = 0; ks < 2; ++ks) {
            const int koff = ks * 32 + g * 8;
            bf16x8 a[4];
            #pragma unroll
            for (int mi = 0; mi < 4; ++mi)
                a[mi] = *reinterpret_cast<const bf16x8*>(&As[cur][(mi * 16 + c) * 72 + koff]);
            #pragma unroll
            for (int mi = 0; mi < 4; ++mi)
                #pragma unroll
                for (int ni = 0; ni < 4; ++ni)
                    acc[mi][ni] = __builtin_amdgcn_mfma_f32_16x16x32_bf16(a[mi], bfrag[ks][ni], acc[mi][ni], 0, 0, 0);
        }
        if (kt + 1 < NKT) writeA(cur ^ 1);     // write-late: loads had compute to land
        __syncthreads();
    }

    float bcol[4];
    #pragma unroll
    for (int ni = 0; ni < 4; ++ni) bcol[ni] = bias[wn0 + ni * 16 + c];

    if constexpr (!NORM) {
        #pragma unroll
        for (int mi = 0; mi < 4; ++mi) {
            int rowb = m0 + mi * 16 + g * 4;
            #pragma unroll
            for (int ni = 0; ni < 4; ++ni) {
                int col = wn0 + ni * 16 + c;
                #pragma unroll
                for (int r = 0; r < 4; ++r) {
                    int row = rowb + r;
                    if (row < M) {
                        float v = fmaxf(acc[mi][ni][r] + bcol[ni], 0.f);
                        Cb[(size_t)row * 256 + col] = f2bf(v);
                    }
                }
            }
        }
    } else {
        float ssq[4][4];
        #pragma unroll
        for (int mi = 0; mi < 4; ++mi) {
            #pragma unroll
            for (int r = 0; r < 4; ++r) {
                float s = 0.f;
                #pragma unroll
                for (int ni = 0; ni < 4; ++ni) {
                    float v = fmaxf(acc[mi][ni][r] + bcol[ni], 0.f);
                    acc[mi][ni][r] = v;
                    s += v * v;
                }
                #pragma unroll
                for (int m = 1; m < 16; m <<= 1) s += __shfl_xor(s, m, 64);
                ssq[mi][r] = s;
            }
        }
        if (c == 0) {
            #pragma unroll
            for (int mi = 0; mi < 4; ++mi)
                #pragma unroll
                for (int r = 0; r < 4; ++r)
                    norml[wave][mi * 16 + g * 4 + r] = ssq[mi][r];
        }
        __syncthreads();
        #pragma unroll
        for (int mi = 0; mi < 4; ++mi) {
            int rowb = m0 + mi * 16 + g * 4;
            #pragma unroll
            for (int r = 0; r < 4; ++r) {
                int rl = mi * 16 + g * 4 + r;
                float tot = norml[0][rl] + norml[1][rl] + norml[2][rl] + norml[3][rl];
                float rn = tot > 0.f ? rsqrtf(tot) : 1.0f;
                int row = rowb + r;
                if (row < M) {
                    #pragma unroll
                    for (int ni = 0; ni < 4; ++ni) {
                        int col = wn0 + ni * 16 + c;
                        Cf[(size_t)row * 256 + col] = acc[mi][ni][r] * rn;
                    }
                }
            }
        }
    }
}

// ---- per-dst aggregation: one wave per dst; unroll-2 on edges to pipeline gathers
__global__ __launch_bounds__(256) void aggregate_kernel(
    const unsigned short* __restrict__ nft, const float* __restrict__ h_dst,
    const float* __restrict__ weights, const int* __restrict__ src_idx,
    const int* __restrict__ edge_list, const int* __restrict__ offsets,
    unsigned short* __restrict__ xb)
{
    int d = blockIdx.x * 4 + (threadIdx.x >> 6);
    if (d >= N_DST) return;
    int lane = threadIdx.x & 63;
    int p0 = offsets[d], p1 = offsets[d + 1];
    float a0 = 0.f, a1 = 0.f, a2 = 0.f, a3 = 0.f, wsum = 0.f;
    int p = p0;
    for (; p + 1 < p1; p += 2) {
        int e0 = edge_list[p], e1 = edge_list[p + 1];
        float w0 = weights[e0], w1 = weights[e1];
        int s0 = src_idx[e0], s1 = src_idx[e1];
        uint2 v0 = *reinterpret_cast<const uint2*>(nft + (size_t)s0 * 256 + lane * 4);
        uint2 v1 = *reinterpret_cast<const uint2*>(nft + (size_t)s1 * 256 + lane * 4);
        wsum += w0 + w1;
        a0 += w0 * bf2f(v0.x & 0xffffu) + w1 * bf2f(v1.x & 0xffffu);
        a1 += w0 * bf2f(v0.x >> 16)     + w1 * bf2f(v1.x >> 16);
        a2 += w0 * bf2f(v0.y & 0xffffu) + w1 * bf2f(v1.y & 0xffffu);
        a3 += w0 * bf2f(v0.y >> 16)     + w1 * bf2f(v1.y >> 16);
    }
    if (p < p1) {
        int e = edge_list[p];
        float w = weights[e];
        int s = src_idx[e];
        wsum += w;
        uint2 v = *reinterpret_cast<const uint2*>(nft + (size_t)s * 256 + lane * 4);
        a0 += w * bf2f(v.x & 0xffffu);
        a1 += w * bf2f(v.x >> 16);
        a2 += w * bf2f(v.y & 0xffffu);
        a3 += w * bf2f(v.y >> 16);
    }
    float inv = 1.0f / fmaxf(wsum, 1.0f);
    uint2 pk;
    pk.x = (unsigned)f2bf(a0 * inv) | ((unsigned)f2bf(a1 * inv) << 16);
    pk.y = (unsigned)f2bf(a2 * inv) | ((unsigned)f2bf(a3 * inv) << 16);
    *reinterpret_cast<uint2*>(xb + (size_t)d * 512 + lane * 4) = pk;
    float4 h = *reinterpret_cast<const float4*>(h_dst + (size_t)d * 256 + lane * 4);
    uint2 q;
    q.x = (unsigned)f2bf(h.x) | ((unsigned)f2bf(h.y) << 16);
    q.y = (unsigned)f2bf(h.z) | ((unsigned)f2bf(h.w) << 16);
    *reinterpret_cast<uint2*>(xb + (size_t)d * 512 + 256 + lane * 4) = q;
}

extern "C" void kernel_launch(void* const* d_in, const int* in_sizes, int n_in,
                              void* d_out, int out_size, void* d_ws, size_t ws_size,
                              hipStream_t stream) {
    const float* h_src   = (const float*)d_in[0];
    const float* h_dst   = (const float*)d_in[1];
    const float* weights = (const float*)d_in[2];
    const float* Q_w     = (const float*)d_in[3];
    const float* Q_b     = (const float*)d_in[4];
    const float* W_w     = (const float*)d_in[5];
    const float* W_b     = (const float*)d_in[6];
    const int* src_idx   = (const int*)d_in[7];
    const int* dst_idx   = (const int*)d_in[8];
    float* out = (float*)d_out;

    char* ws = (char*)d_ws;
    unsigned short* nft = (unsigned short*)(ws);               // 51,200,000
    unsigned short* xb  = (unsigned short*)(ws + 51200000);    // 25,600,000
    unsigned short* Qt  = (unsigned short*)(ws + 76800000);    // 131,072
    unsigned short* Wt  = (unsigned short*)(ws + 76931072);    // 262,144
    int* counts    = (int*)(ws + 77193216);                    // 100,000
    int* offsets   = (int*)(ws + 77293216);                    // 100,004
    int* edge_list = (int*)(ws + 77393220);                    // 1,200,000 (~78.6 MB total)

    hipMemsetAsync(counts, 0, N_DST * sizeof(int), stream);

    cast_weights<<<768, 256, 0, stream>>>(Q_w, W_w, Qt, Wt);
    hist_kernel<<<(N_EDGE + 255) / 256, 256, 0, stream>>>(dst_idx, counts);
    scan_kernel<<<1, 1024, 0, stream>>>(counts, offsets, N_DST);
    scatter_kernel<<<(N_EDGE + 255) / 256, 256, 0, stream>>>(dst_idx, offsets, counts, edge_list);

    gemm_fused<256, false, false><<<(N_SRC + 63) / 64, 256, 0, stream>>>(
        h_src, nullptr, Qt, Q_b, nft, nullptr, N_SRC);

    aggregate_kernel<<<N_DST / 4, 256, 0, stream>>>(
        nft, h_dst, weights, src_idx, edge_list, offsets, xb);

    gemm_fused<512, true, true><<<(N_DST + 63) / 64, 256, 0, stream>>>(
        nullptr, xb, Wt, W_b, nullptr, out, N_DST);

    (void)in_sizes; (void)n_in; (void)out_size; (void)ws_size;
}